// Round 2
// baseline (2450.495 us; speedup 1.0000x reference)
//
#include <hip/hip_runtime.h>
#include <stdint.h>

// GoalDecoderLSTM: B=131072 independent LSTM decoders, H=64, E=16, SEQ=30.
// R2: round-1 NaN diagnosed as dtype misread (reference declares f32; we read
// bf16). NaN is arithmetically unreachable under bf16 inputs, so inputs are
// almost certainly f32. Insurance: device-side dtype sniff (setup kernel) +
// both dtype-templated decoders launched each call, early-exit on flag
// mismatch. Core: wave=16 batch elems, lane=hidden unit, weights register-
// resident as f16 pairs, h broadcast lane-pack + readlane, v_dot2_f32_f16.

#define B_TOT 131072
#define SEQL 30

typedef _Float16 h2v __attribute__((ext_vector_type(2)));

#if __has_builtin(__builtin_amdgcn_fdot2)
#define HAVE_FDOT2 1
#else
#define HAVE_FDOT2 0
#endif

__device__ __forceinline__ float bf2f(uint32_t v) {
  return __builtin_bit_cast(float, v << 16);
}
__device__ __forceinline__ uint32_t f2bf_rne(float f) {
  uint32_t u = __builtin_bit_cast(uint32_t, f);
  return (u + 0x7fffu + ((u >> 16) & 1u)) >> 16;
}
// Runtime-dtype scalar load: bf16 (raw u16) or f32, same element index.
__device__ __forceinline__ float ldrt(const void* p, int idx, bool bf16) {
  if (bf16) return bf2f(((const uint16_t*)p)[idx]);
  return ((const float*)p)[idx];
}
__device__ __forceinline__ float fexp2(float x) {
#if __has_builtin(__builtin_amdgcn_exp2f)
  return __builtin_amdgcn_exp2f(x);
#else
  return exp2f(x);
#endif
}
__device__ __forceinline__ float frcp(float x) {
#if __has_builtin(__builtin_amdgcn_rcpf)
  return __builtin_amdgcn_rcpf(x);
#else
  return 1.0f / x;
#endif
}
__device__ __forceinline__ float fsigmoid(float x) {
  return frcp(1.0f + fexp2(-1.4426950408889634f * x));
}
__device__ __forceinline__ float ftanh(float x) {
  return 1.0f - 2.0f * frcp(1.0f + fexp2(2.8853900817779268f * x));
}
__device__ __forceinline__ float dot2a(h2v a, h2v b, float acc) {
#if HAVE_FDOT2
  return __builtin_amdgcn_fdot2(a, b, acc, false);
#else
  return fmaf((float)a[0], (float)b[0], fmaf((float)a[1], (float)b[1], acc));
#endif
}
__device__ __forceinline__ float wave_sum(float v) {
#pragma unroll
  for (int off = 1; off < 64; off <<= 1) v += __shfl_xor(v, off, 64);
  return v;
}

// ws layout (floats): [0:64] M0, [64:128] M1,
// [128..135] Sx0,Sx1,Sy0,Sy1,Sb0,Sb1,C00,C01, [136] dtype flag (1=bf16).
__global__ void setup_consts(const void* __restrict__ h0,
                             const void* __restrict__ Wgoal,
                             const void* __restrict__ bgoal,
                             const void* __restrict__ Wh2p,
                             const void* __restrict__ bh2p,
                             const void* __restrict__ Wabs,
                             const void* __restrict__ babs,
                             float* __restrict__ wsf) {
  const int k = threadIdx.x;  // 0..63, one wave
  // dtype sniff: low-16 "bf16 exponent" of h0 words. f32 N(0,1): uniform
  // (~12/64 in range). bf16-packed: ~64/64 in range.
  uint32_t w = ((const uint32_t*)h0)[k];
  uint32_t e = (w >> 7) & 0xffu;
  bool inr = (e >= 96u) && (e <= 144u);
  int cnt = (int)__popcll(__ballot(inr));
  const bool bf16 = cnt >= 40;
  if (k == 0) ((uint32_t*)wsf)[136] = bf16 ? 1u : 0u;

  float s0 = 0.f, s1 = 0.f;
  for (int jj = 0; jj < 64; ++jj) {
    float wg = ldrt(Wgoal, jj * 64 + k, bf16);  // W_goal[jj][k], (64,64)
    s0 += wg * ldrt(Wh2p, 128 + jj, bf16);      // row0 goal section
    s1 += wg * ldrt(Wh2p, 320 + jj, bf16);      // row1 goal section
  }
  wsf[k] = s0;
  wsf[64 + k] = s1;
  if (k == 0) {
    for (int p = 0; p < 2; ++p) {
      float sx = 0.f, sy = 0.f, sb = 0.f, cg = 0.f;
      for (int jj = 0; jj < 64; ++jj) {
        float wv = ldrt(Wh2p, p * 192 + 64 + jj, bf16);  // abs section
        sx += ldrt(Wabs, jj * 2 + 0, bf16) * wv;
        sy += ldrt(Wabs, jj * 2 + 1, bf16) * wv;
        sb += ldrt(babs, jj, bf16) * wv;
        cg += ldrt(bgoal, jj, bf16) * ldrt(Wh2p, p * 192 + 128 + jj, bf16);
      }
      wsf[128 + p] = sx;
      wsf[130 + p] = sy;
      wsf[132 + p] = sb + ldrt(bh2p, p, bf16);
      wsf[134 + p] = cg;
    }
  }
}

template <int BF16>
__global__ __launch_bounds__(256, 2) void lstm_decode(
    const void* __restrict__ tabs, const void* __restrict__ trel,
    const void* __restrict__ h0, const void* __restrict__ c0,
    const void* __restrict__ goals, const void* __restrict__ Wih,
    const void* __restrict__ Whh, const void* __restrict__ bih,
    const void* __restrict__ bhh, const void* __restrict__ Wse,
    const void* __restrict__ bse, const void* __restrict__ Wh2p,
    const float* __restrict__ wsf, void* __restrict__ outp) {
  // dtype gate: only the matching variant proceeds.
  if (((const uint32_t*)wsf)[136] != (uint32_t)BF16) return;
  const bool bf = (BF16 != 0);
  const int lane = threadIdx.x & 63;
  const int waveg = blockIdx.x * (blockDim.x >> 6) + (threadIdx.x >> 6);
  const int j = lane;

  // ---- register-resident weights as f16 pairs ----
  h2v whh2[4][32];
  h2v wih2[4][8];
  float bias[4];
#pragma unroll
  for (int g = 0; g < 4; ++g) {
    const int row = g * 64 + j;
#pragma unroll
    for (int kk = 0; kk < 32; ++kk) {
      h2v w;
      w[0] = (_Float16)ldrt(Whh, row * 64 + 2 * kk, bf);
      w[1] = (_Float16)ldrt(Whh, row * 64 + 2 * kk + 1, bf);
      whh2[g][kk] = w;
    }
#pragma unroll
    for (int kk = 0; kk < 8; ++kk) {
      h2v w;
      w[0] = (_Float16)ldrt(Wih, row * 16 + 2 * kk, bf);
      w[1] = (_Float16)ldrt(Wih, row * 16 + 2 * kk + 1, bf);
      wih2[g][kk] = w;
    }
    bias[g] = ldrt(bih, row, bf) + ldrt(bhh, row, bf);
  }
  const float wp0 = ldrt(Wh2p, j, bf);
  const float wp1 = ldrt(Wh2p, 192 + j, bf);
  const int xi = j & 15;
  const float wse0 = ldrt(Wse, xi * 2 + 0, bf);
  const float wse1 = ldrt(Wse, xi * 2 + 1, bf);
  const float bse0 = ldrt(bse, xi, bf);
  const float m0 = wsf[j], m1 = wsf[64 + j];
  const float Sx0 = wsf[128], Sx1 = wsf[129];
  const float Sy0 = wsf[130], Sy1 = wsf[131];
  const float Sb0 = wsf[132], Sb1 = wsf[133];
  const float C00 = wsf[134], C01 = wsf[135];

  for (int e = 0; e < 16; ++e) {
    const int b = waveg * 16 + e;
    float h = ldrt(h0, b * 64 + j, bf);
    float c = ldrt(c0, b * 64 + j, bf);
    float ax = ldrt(tabs, b * 2 + 0, bf);
    float ay = ldrt(tabs, b * 2 + 1, bf);
    float gl = ldrt(goals, b * 64 + j, bf);  // goals flat (b, 64)
    float G0 = wave_sum(gl * m0) + C00;
    float G1 = wave_sum(gl * m1) + C01;
    float r0 = ldrt(trel, b * 2 + 0, bf);
    float r1 = ldrt(trel, b * 2 + 1, bf);
    float t = fmaf(r0, wse0, fmaf(r1, wse1, bse0));
    float xf = t >= 0.0f ? t : 0.01f * t;
    float xe = __shfl(xf, 2 * (lane & 7), 64);
    float xo = __shfl(xf, 2 * (lane & 7) + 1, 64);
    h2v xp;
    xp[0] = (_Float16)xe;
    xp[1] = (_Float16)xo;
    int xpi = __builtin_bit_cast(int, xp);

    for (int s = 0; s < SEQL; ++s) {
      float he = __shfl(h, (2 * lane) & 63, 64);
      float ho = __shfl(h, (2 * lane + 1) & 63, 64);
      h2v hp;
      hp[0] = (_Float16)he;
      hp[1] = (_Float16)ho;
      int hpi = __builtin_bit_cast(int, hp);

      float a0 = bias[0], a1 = bias[1], a2 = bias[2], a3 = bias[3];
#pragma unroll
      for (int kk = 0; kk < 32; ++kk) {
        h2v hh = __builtin_bit_cast(h2v, __builtin_amdgcn_readlane(hpi, kk));
        a0 = dot2a(whh2[0][kk], hh, a0);
        a1 = dot2a(whh2[1][kk], hh, a1);
        a2 = dot2a(whh2[2][kk], hh, a2);
        a3 = dot2a(whh2[3][kk], hh, a3);
      }
#pragma unroll
      for (int kk = 0; kk < 8; ++kk) {
        h2v xx = __builtin_bit_cast(h2v, __builtin_amdgcn_readlane(xpi, kk));
        a0 = dot2a(wih2[0][kk], xx, a0);
        a1 = dot2a(wih2[1][kk], xx, a1);
        a2 = dot2a(wih2[2][kk], xx, a2);
        a3 = dot2a(wih2[3][kk], xx, a3);
      }
      // gate order: i, f, g, o
      float si = fsigmoid(a0);
      float sf = fsigmoid(a1);
      float tg = ftanh(a2);
      float so = fsigmoid(a3);
      c = fmaf(sf, c, si * tg);
      h = so * ftanh(c);

      float p0 = wave_sum(h * wp0);
      float p1 = wave_sum(h * wp1);
      float rel0 = p0 + G0 + fmaf(ax, Sx0, fmaf(ay, Sy0, Sb0));
      float rel1 = p1 + G1 + fmaf(ax, Sx1, fmaf(ay, Sy1, Sb1));
      ax += rel0;
      ay += rel1;
      if (lane == 0) {
        if (BF16) {
          ((uint32_t*)outp)[s * B_TOT + b] =
              f2bf_rne(rel0) | (f2bf_rne(rel1) << 16);
        } else {
          float2 v;
          v.x = rel0;
          v.y = rel1;
          ((float2*)outp)[s * B_TOT + b] = v;
        }
      }
      float tx = fmaf(rel0, wse0, fmaf(rel1, wse1, bse0));
      xf = tx >= 0.0f ? tx : 0.01f * tx;
      xe = __shfl(xf, 2 * (lane & 7), 64);
      xo = __shfl(xf, 2 * (lane & 7) + 1, 64);
      xp[0] = (_Float16)xe;
      xp[1] = (_Float16)xo;
      xpi = __builtin_bit_cast(int, xp);
    }
  }
}

extern "C" void kernel_launch(void* const* d_in, const int* in_sizes, int n_in,
                              void* d_out, int out_size, void* d_ws,
                              size_t ws_size, hipStream_t stream) {
  (void)in_sizes; (void)n_in; (void)out_size; (void)ws_size;
  const void* tabs  = d_in[0];
  const void* trel  = d_in[1];
  const void* h0    = d_in[2];
  const void* c0    = d_in[3];
  const void* goals = d_in[4];
  const void* Wih   = d_in[5];
  const void* Whh   = d_in[6];
  const void* bih   = d_in[7];
  const void* bhh   = d_in[8];
  const void* Wse   = d_in[9];
  const void* bse   = d_in[10];
  const void* Wh2p  = d_in[11];
  const void* bh2p  = d_in[12];
  const void* Wgoal = d_in[13];
  const void* bgoal = d_in[14];
  const void* Wabs  = d_in[15];
  const void* babs  = d_in[16];
  float* wsf = (float*)d_ws;

  setup_consts<<<dim3(1), dim3(64), 0, stream>>>(h0, Wgoal, bgoal, Wh2p, bh2p,
                                                 Wabs, babs, wsf);
  // 2048 blocks * 4 waves * 16 elems = 131072; both dtype variants launch,
  // the non-matching one early-exits on the ws flag.
  lstm_decode<0><<<dim3(2048), dim3(256), 0, stream>>>(
      tabs, trel, h0, c0, goals, Wih, Whh, bih, bhh, Wse, bse, Wh2p, wsf,
      d_out);
  lstm_decode<1><<<dim3(2048), dim3(256), 0, stream>>>(
      tabs, trel, h0, c0, goals, Wih, Whh, bih, bhh, Wse, bse, Wh2p, wsf,
      d_out);
}

// Round 3
// 709.806 us; speedup vs baseline: 3.4523x; 3.4523x over previous
//
#include <hip/hip_runtime.h>
#include <stdint.h>

// GoalDecoderLSTM: B=131072 indep LSTM decoders, H=64, E=16, SEQ=30.
// R3: MFMA restructure. Block = 4 waves = 16 batch elems. Wave w owns hidden
// slice [16w,16w+16) = 4 N-tiles (one per gate i/f/g/o), K=80 (h64+x16) in 3
// K-steps of mfma_f32_16x16x32_f16. Weight B-frags register-resident f16
// (48 VGPR). h round-trips through double-buffered LDS (row stride 72 f16 ->
// 2-way bank aliasing = free), ONE barrier/step. rel (output proj) computed
// redundantly per wave via 2 MFMAs vs W_h2p cols {0,1}; goal/abs terms folded
// to per-batch scalars (R2 setup kernel). Dual-dtype insurance kept (flag in
// ws; both template variants launch, mismatch early-exits).

#define B_TOT 131072
#define SEQL 30

typedef _Float16 f16x8 __attribute__((ext_vector_type(8)));
typedef float f32x4 __attribute__((ext_vector_type(4)));

__device__ __forceinline__ float bf2f(uint32_t v) {
  return __builtin_bit_cast(float, v << 16);
}
__device__ __forceinline__ uint32_t f2bf_rne(float f) {
  uint32_t u = __builtin_bit_cast(uint32_t, f);
  return (u + 0x7fffu + ((u >> 16) & 1u)) >> 16;
}
__device__ __forceinline__ float ldrt(const void* p, int idx, bool bf16) {
  if (bf16) return bf2f(((const uint16_t*)p)[idx]);
  return ((const float*)p)[idx];
}
__device__ __forceinline__ float fexp2(float x) {
#if __has_builtin(__builtin_amdgcn_exp2f)
  return __builtin_amdgcn_exp2f(x);
#else
  return exp2f(x);
#endif
}
__device__ __forceinline__ float frcp(float x) {
#if __has_builtin(__builtin_amdgcn_rcpf)
  return __builtin_amdgcn_rcpf(x);
#else
  return 1.0f / x;
#endif
}
__device__ __forceinline__ float fsigmoid(float x) {
  return frcp(1.0f + fexp2(-1.4426950408889634f * x));
}
__device__ __forceinline__ float ftanh(float x) {
  return 1.0f - 2.0f * frcp(1.0f + fexp2(2.8853900817779268f * x));
}

// ws layout (floats): [0:64] M0, [64:128] M1,
// [128..135] Sx0,Sx1,Sy0,Sy1,Sb0,Sb1,C00,C01, [136] dtype flag (1=bf16).
__global__ void setup_consts(const void* __restrict__ h0,
                             const void* __restrict__ Wgoal,
                             const void* __restrict__ bgoal,
                             const void* __restrict__ Wh2p,
                             const void* __restrict__ bh2p,
                             const void* __restrict__ Wabs,
                             const void* __restrict__ babs,
                             float* __restrict__ wsf) {
  const int k = threadIdx.x;  // 0..63, one wave
  uint32_t w = ((const uint32_t*)h0)[k];
  uint32_t e = (w >> 7) & 0xffu;
  bool inr = (e >= 96u) && (e <= 144u);
  int cnt = (int)__popcll(__ballot(inr));
  const bool bf16 = cnt >= 40;
  if (k == 0) ((uint32_t*)wsf)[136] = bf16 ? 1u : 0u;

  float s0 = 0.f, s1 = 0.f;
  for (int jj = 0; jj < 64; ++jj) {
    float wg = ldrt(Wgoal, jj * 64 + k, bf16);  // W_goal[jj][k], (64,64)
    s0 += wg * ldrt(Wh2p, 128 + jj, bf16);
    s1 += wg * ldrt(Wh2p, 320 + jj, bf16);
  }
  wsf[k] = s0;
  wsf[64 + k] = s1;
  if (k == 0) {
    for (int p = 0; p < 2; ++p) {
      float sx = 0.f, sy = 0.f, sb = 0.f, cg = 0.f;
      for (int jj = 0; jj < 64; ++jj) {
        float wv = ldrt(Wh2p, p * 192 + 64 + jj, bf16);
        sx += ldrt(Wabs, jj * 2 + 0, bf16) * wv;
        sy += ldrt(Wabs, jj * 2 + 1, bf16) * wv;
        sb += ldrt(babs, jj, bf16) * wv;
        cg += ldrt(bgoal, jj, bf16) * ldrt(Wh2p, p * 192 + 128 + jj, bf16);
      }
      wsf[128 + p] = sx;
      wsf[130 + p] = sy;
      wsf[132 + p] = sb + ldrt(bh2p, p, bf16);
      wsf[134 + p] = cg;
    }
  }
}

template <int BF16>
__global__ __launch_bounds__(256, 3) void lstm_mfma(
    const void* __restrict__ tabs, const void* __restrict__ trel,
    const void* __restrict__ h0, const void* __restrict__ c0,
    const void* __restrict__ goals, const void* __restrict__ Wih,
    const void* __restrict__ Whh, const void* __restrict__ bih,
    const void* __restrict__ bhh, const void* __restrict__ Wse,
    const void* __restrict__ bse, const void* __restrict__ Wh2p,
    const float* __restrict__ wsf, void* __restrict__ outp) {
  if (((const uint32_t*)wsf)[136] != (uint32_t)BF16) return;
  const bool bf = (BF16 != 0);
  const int lane = threadIdx.x & 63;
  const int w = threadIdx.x >> 6;  // wave in block: hidden slice [16w,16w+16)
  const int q = lane >> 4;         // quad
  const int n = lane & 15;         // N-col (gate sub-col) / M-row (batch)
  const int hs = 16 * w;
  const int bbase = blockIdx.x * 16;

  // double-buffered h exchange: row stride 72 f16 (144B) -> 2-way bank alias
  __shared__ __align__(16) _Float16 hbuf[2 * 16 * 72];

  // ---- gate weight B-fragments: B[k][gcol] = Wcat[gcol][k], f16 ----
  // gcol = g*64 + hs + n ; k = kk*32 + q*8 + j (kk=2: x part, k-64<16)
  f16x8 bw[4][3];
  float bias[4];
#pragma unroll
  for (int g = 0; g < 4; ++g) {
    const int row = g * 64 + hs + n;
#pragma unroll
    for (int kk = 0; kk < 2; ++kk)
#pragma unroll
      for (int j = 0; j < 8; ++j)
        bw[g][kk][j] = (_Float16)ldrt(Whh, row * 64 + kk * 32 + q * 8 + j, bf);
#pragma unroll
    for (int j = 0; j < 8; ++j)
      bw[g][2][j] = (q < 2) ? (_Float16)ldrt(Wih, row * 16 + q * 8 + j, bf)
                            : (_Float16)0.f;
    bias[g] = ldrt(bih, row, bf) + ldrt(bhh, row, bf);
  }
  // ---- rel-projection B-fragments: col0 = W_h2p[0][k], col1 = W_h2p[1][k]
  f16x8 bp[2];
#pragma unroll
  for (int kk = 0; kk < 2; ++kk)
#pragma unroll
    for (int j = 0; j < 8; ++j) {
      int k = kk * 32 + q * 8 + j;
      float v = (n == 0) ? ldrt(Wh2p, k, bf)
                         : ((n == 1) ? ldrt(Wh2p, 192 + k, bf) : 0.f);
      bp[kk][j] = (_Float16)v;
    }
  const int np = (n == 1) ? 1 : 0;
  const float Sxn = wsf[128 + np], Syn = wsf[130 + np];
  const float SbCn = wsf[132 + np] + wsf[134 + np];  // Sb + C0 folded

  // ---- Wse rows for x rebuild (lane handles x[batch=n][q*8+j], q<2) ----
  float wsa[8], wsb[8], bsc[8];
#pragma unroll
  for (int j = 0; j < 8; ++j) {
    if (q < 2) {
      int kx = q * 8 + j;
      wsa[j] = ldrt(Wse, kx * 2 + 0, bf);
      wsb[j] = ldrt(Wse, kx * 2 + 1, bf);
      bsc[j] = ldrt(bse, kx, bf);
    } else {
      wsa[j] = 0.f; wsb[j] = 0.f; bsc[j] = 0.f;
    }
  }

  const f32x4 z = {0.f, 0.f, 0.f, 0.f};
  // ---- goal term via MFMA: G[b] partial, D layout matches rel's ----
  f32x4 Gacc = z;
#pragma unroll
  for (int kk = 0; kk < 2; ++kk) {
    f16x8 ag, bm;
#pragma unroll
    for (int j = 0; j < 8; ++j) {
      int k = kk * 32 + q * 8 + j;
      ag[j] = (_Float16)ldrt(goals, (bbase + n) * 64 + k, bf);  // A[m=n][k]
      float mv = (n == 0) ? wsf[k] : ((n == 1) ? wsf[64 + k] : 0.f);
      bm[j] = (_Float16)mv;
    }
    Gacc = __builtin_amdgcn_mfma_f32_16x16x32_f16(ag, bm, Gacc, 0, 0, 0);
  }

  // ---- per-batch abs_pos (meaningful at n<2 lanes; reg r -> batch 4q+r) ---
  float axv[4], ayv[4], cst[4];
#pragma unroll
  for (int r = 0; r < 4; ++r) {
    const int b = bbase + 4 * q + r;
    axv[r] = ldrt(tabs, b * 2 + 0, bf);
    ayv[r] = ldrt(tabs, b * 2 + 1, bf);
    cst[r] = ldrt(c0, b * 64 + hs + n, bf);
    hbuf[(4 * q + r) * 72 + hs + n] = (_Float16)ldrt(h0, b * 64 + hs + n, bf);
  }

  // ---- x_0 from trel: x[batch=n][q*8+j] = lrelu(trel @ Wse^T + bse) ----
  float tr0 = ldrt(trel, (bbase + n) * 2 + 0, bf);
  float tr1 = ldrt(trel, (bbase + n) * 2 + 1, bf);
  f16x8 xf;
#pragma unroll
  for (int j = 0; j < 8; ++j) {
    float t = fmaf(tr0, wsa[j], fmaf(tr1, wsb[j], bsc[j]));
    t = t >= 0.f ? t : 0.01f * t;
    xf[j] = (q < 2) ? (_Float16)t : (_Float16)0.f;
  }

  int p = 0;
  for (int s = 0; s <= SEQL; ++s) {
    __syncthreads();  // hbuf[p] now holds h_s for all 64 hidden units
    const _Float16* hb = &hbuf[p * 1152];
    f16x8 ah0 = *(const f16x8*)(hb + n * 72 + q * 8);       // A[m=n][k<32]
    f16x8 ah1 = *(const f16x8*)(hb + n * 72 + 32 + q * 8);  // k in [32,64)

    if (s > 0) {
      // rel_{s-1} = h_s @ W_h2p_h^T + folded terms
      f32x4 pa = __builtin_amdgcn_mfma_f32_16x16x32_f16(ah0, bp[0], z, 0, 0, 0);
      pa = __builtin_amdgcn_mfma_f32_16x16x32_f16(ah1, bp[1], pa, 0, 0, 0);
      float u[4], rel0[4], rel1[4];
#pragma unroll
      for (int r = 0; r < 4; ++r) {
        u[r] = pa[r] + Gacc[r] + SbCn + fmaf(axv[r], Sxn, ayv[r] * Syn);
        float v = __shfl_xor(u[r], 1, 64);
        rel0[r] = (np == 0) ? u[r] : v;
        rel1[r] = (np == 0) ? v : u[r];
        axv[r] += rel0[r];
        ayv[r] += rel1[r];
      }
      if (w == 0 && n < 2) {
#pragma unroll
        for (int r = 0; r < 4; ++r) {
          const int b = bbase + 4 * q + r;
          if (BF16) {
            if (n == 0)
              ((uint32_t*)outp)[(size_t)(s - 1) * B_TOT + b] =
                  f2bf_rne(rel0[r]) | (f2bf_rne(rel1[r]) << 16);
          } else {
            ((float*)outp)[((size_t)(s - 1) * B_TOT + b) * 2 + n] = u[r];
          }
        }
      }
      // broadcast rel to batch-owner lanes: batch m=lane&15 lives at
      // lane ((m>>2)<<4)+0, register m&3
      const int src = ((lane & 15) >> 2) << 4;
      float t0[4], t1[4];
#pragma unroll
      for (int r = 0; r < 4; ++r) {
        t0[r] = __shfl(rel0[r], src, 64);
        t1[r] = __shfl(rel1[r], src, 64);
      }
      const int rs = lane & 3;
      float rb0 = rs == 0 ? t0[0] : rs == 1 ? t0[1] : rs == 2 ? t0[2] : t0[3];
      float rb1 = rs == 0 ? t1[0] : rs == 1 ? t1[1] : rs == 2 ? t1[2] : t1[3];
#pragma unroll
      for (int j = 0; j < 8; ++j) {
        float t = fmaf(rb0, wsa[j], fmaf(rb1, wsb[j], bsc[j]));
        t = t >= 0.f ? t : 0.01f * t;
        xf[j] = (q < 2) ? (_Float16)t : (_Float16)0.f;
      }
    }

    if (s < SEQL) {
      f32x4 acc[4];
#pragma unroll
      for (int g = 0; g < 4; ++g) {
        f32x4 a = {bias[g], bias[g], bias[g], bias[g]};
        a = __builtin_amdgcn_mfma_f32_16x16x32_f16(ah0, bw[g][0], a, 0, 0, 0);
        a = __builtin_amdgcn_mfma_f32_16x16x32_f16(ah1, bw[g][1], a, 0, 0, 0);
        a = __builtin_amdgcn_mfma_f32_16x16x32_f16(xf, bw[g][2], a, 0, 0, 0);
        acc[g] = a;
      }
      _Float16* hw = &hbuf[(p ^ 1) * 1152];
#pragma unroll
      for (int r = 0; r < 4; ++r) {
        float iv = fsigmoid(acc[0][r]);
        float fv = fsigmoid(acc[1][r]);
        float gv = ftanh(acc[2][r]);
        float ov = fsigmoid(acc[3][r]);
        cst[r] = fmaf(fv, cst[r], iv * gv);
        float hn = ov * ftanh(cst[r]);
        hw[(4 * q + r) * 72 + hs + n] = (_Float16)hn;
      }
      p ^= 1;
    }
  }
}

extern "C" void kernel_launch(void* const* d_in, const int* in_sizes, int n_in,
                              void* d_out, int out_size, void* d_ws,
                              size_t ws_size, hipStream_t stream) {
  (void)in_sizes; (void)n_in; (void)out_size; (void)ws_size;
  const void* tabs  = d_in[0];
  const void* trel  = d_in[1];
  const void* h0    = d_in[2];
  const void* c0    = d_in[3];
  const void* goals = d_in[4];
  const void* Wih   = d_in[5];
  const void* Whh   = d_in[6];
  const void* bih   = d_in[7];
  const void* bhh   = d_in[8];
  const void* Wse   = d_in[9];
  const void* bse   = d_in[10];
  const void* Wh2p  = d_in[11];
  const void* bh2p  = d_in[12];
  const void* Wgoal = d_in[13];
  const void* bgoal = d_in[14];
  const void* Wabs  = d_in[15];
  const void* babs  = d_in[16];
  float* wsf = (float*)d_ws;

  setup_consts<<<dim3(1), dim3(64), 0, stream>>>(h0, Wgoal, bgoal, Wh2p, bh2p,
                                                 Wabs, babs, wsf);
  // 8192 blocks * 16 batch/block = 131072. Both dtype variants launch; the
  // non-matching one early-exits on the ws flag.
  lstm_mfma<0><<<dim3(8192), dim3(256), 0, stream>>>(
      tabs, trel, h0, c0, goals, Wih, Whh, bih, bhh, Wse, bse, Wh2p, wsf,
      d_out);
  lstm_mfma<1><<<dim3(8192), dim3(256), 0, stream>>>(
      tabs, trel, h0, c0, goals, Wih, Whh, bih, bhh, Wse, bse, Wh2p, wsf,
      d_out);
}

// Round 4
// 586.574 us; speedup vs baseline: 4.1776x; 1.2101x over previous
//
#include <hip/hip_runtime.h>
#include <stdint.h>

// GoalDecoderLSTM: B=131072 indep LSTM decoders, H=64, E=16, SEQ=30. f32 I/O
// (proven by R3: dtype-sniff chose f32 and passed).
// R4: VALU trim on the R3 MFMA structure. Changes:
//  - single f32 kernel (dead bf16 variant + sniff dropped)
//  - setup kernel parallelized (was ~20us serial lane-0 loops)
//  - rel broadcast via per-wave LDS scratch (no barrier needed: same-wave
//    LDS write->read), replacing 8 shfl + ~14 selects
//  - x-rebuild in packed f16 (v_pk_fma, lrelu = 0.505x+0.495|x| via bitmask)
// Activations stay exact f32 exp2/rcp (accuracy-safe); pk-f16 activation
// pipeline is the next lever if VALUBusy stays ~77%.

#define B_TOT 131072
#define SEQL 30

typedef _Float16 f16x8 __attribute__((ext_vector_type(8)));
typedef _Float16 f16x2 __attribute__((ext_vector_type(2)));
typedef float f32x4 __attribute__((ext_vector_type(4)));

__device__ __forceinline__ float fexp2(float x) {
#if __has_builtin(__builtin_amdgcn_exp2f)
  return __builtin_amdgcn_exp2f(x);
#else
  return exp2f(x);
#endif
}
__device__ __forceinline__ float frcp(float x) {
#if __has_builtin(__builtin_amdgcn_rcpf)
  return __builtin_amdgcn_rcpf(x);
#else
  return 1.0f / x;
#endif
}
__device__ __forceinline__ float fsigmoid(float x) {
  return frcp(1.0f + fexp2(-1.4426950408889634f * x));
}
__device__ __forceinline__ float ftanh(float x) {
  return 1.0f - 2.0f * frcp(1.0f + fexp2(2.8853900817779268f * x));
}

// ws layout (floats): [0:64] M0, [64:128] M1,
// [128..135] Sx0,Sx1,Sy0,Sy1,Sb0,Sb1,C00,C01.
__global__ void setup_consts(const float* __restrict__ Wgoal,
                             const float* __restrict__ bgoal,
                             const float* __restrict__ Wh2p,
                             const float* __restrict__ bh2p,
                             const float* __restrict__ Wabs,
                             const float* __restrict__ babs,
                             float* __restrict__ wsf) {
  const int tid = threadIdx.x;
  const int wv = tid >> 6;
  const int lane = tid & 63;
  if (wv == 0) {
    // M_p[k] = sum_j Wgoal[j][k] * Wh2p[p][128+j]; lane=k, parallel over k.
    const int k = lane;
    float s0 = 0.f, s1 = 0.f;
#pragma unroll 8
    for (int jj = 0; jj < 64; ++jj) {
      float wg = Wgoal[jj * 64 + k];
      s0 += wg * Wh2p[128 + jj];
      s1 += wg * Wh2p[320 + jj];
    }
    wsf[k] = s0;
    wsf[64 + k] = s1;
  } else {
    // 8 folded scalars, one per 8-lane group: i = lane>>3 in
    // {Sx0,Sx1,Sy0,Sy1,Sb0,Sb1,C00,C01}; p=i&1, grp=i>>1.
    const int i = lane >> 3, sub = lane & 7;
    const int p = i & 1, grp = i >> 1;
    float s = 0.f;
#pragma unroll
    for (int t = 0; t < 8; ++t) {
      int j = sub * 8 + t;
      float wv_ = (grp < 3) ? Wh2p[p * 192 + 64 + j] : Wh2p[p * 192 + 128 + j];
      float av = (grp == 0)   ? Wabs[j * 2 + 0]
                 : (grp == 1) ? Wabs[j * 2 + 1]
                 : (grp == 2) ? babs[j]
                              : bgoal[j];
      s += av * wv_;
    }
    s += __shfl_xor(s, 1, 64);
    s += __shfl_xor(s, 2, 64);
    s += __shfl_xor(s, 4, 64);
    if (sub == 0) {
      if (grp == 2) s += bh2p[p];
      wsf[128 + i] = s;
    }
  }
}

__global__ __launch_bounds__(256, 3) void lstm_mfma(
    const float* __restrict__ tabs, const float* __restrict__ trel,
    const float* __restrict__ h0, const float* __restrict__ c0,
    const float* __restrict__ goals, const float* __restrict__ Wih,
    const float* __restrict__ Whh, const float* __restrict__ bih,
    const float* __restrict__ bhh, const float* __restrict__ Wse,
    const float* __restrict__ bse, const float* __restrict__ Wh2p,
    const float* __restrict__ wsf, float* __restrict__ outp) {
  const int lane = threadIdx.x & 63;
  const int w = threadIdx.x >> 6;  // wave: hidden slice [16w,16w+16)
  const int q = lane >> 4;         // quad
  const int n = lane & 15;         // N-col / batch-row index
  const int hs = 16 * w;
  const int bbase = blockIdx.x * 16;

  // h exchange: double-buffered, row stride 72 f16 (2-way bank alias = free)
  __shared__ __align__(16) _Float16 hbuf[2 * 16 * 72];
  // per-wave rel scratch: [wave][batch][p] (same-wave write->read, no barrier)
  __shared__ __align__(8) float relbuf[4][16][2];

  // ---- gate weight B-frags: B[k][gcol]=Wcat[gcol][k]; gcol=g*64+hs+n ----
  f16x8 bw[4][3];
  float bias[4];
#pragma unroll
  for (int g = 0; g < 4; ++g) {
    const int row = g * 64 + hs + n;
#pragma unroll
    for (int kk = 0; kk < 2; ++kk)
#pragma unroll
      for (int j = 0; j < 8; ++j)
        bw[g][kk][j] = (_Float16)Whh[row * 64 + kk * 32 + q * 8 + j];
#pragma unroll
    for (int j = 0; j < 8; ++j)
      bw[g][2][j] = (q < 2) ? (_Float16)Wih[row * 16 + q * 8 + j]
                            : (_Float16)0.f;
    bias[g] = bih[row] + bhh[row];
  }
  // ---- rel projection B-frags: col0 = W_h2p[0][k], col1 = W_h2p[1][k] ----
  f16x8 bp0, bp1;
#pragma unroll
  for (int kk = 0; kk < 2; ++kk)
#pragma unroll
    for (int j = 0; j < 8; ++j) {
      int k = kk * 32 + q * 8 + j;
      float v = (n == 0) ? Wh2p[k] : ((n == 1) ? Wh2p[192 + k] : 0.f);
      if (kk == 0) bp0[j] = (_Float16)v; else bp1[j] = (_Float16)v;
    }
  const int np = (n == 1) ? 1 : 0;
  const float Sxn = wsf[128 + np], Syn = wsf[130 + np];
  const float SbCn = wsf[132 + np] + wsf[134 + np];

  // ---- Wse consts as pk pairs for x rebuild: x[batch=n][k=q*8+j] ----
  f16x2 wsaP[4], wsbP[4], bscP[4];
#pragma unroll
  for (int jj = 0; jj < 4; ++jj) {
    if (q < 2) {
      int kx = q * 8 + 2 * jj;
      wsaP[jj] = f16x2{(_Float16)Wse[kx * 2 + 0], (_Float16)Wse[kx * 2 + 2]};
      wsbP[jj] = f16x2{(_Float16)Wse[kx * 2 + 1], (_Float16)Wse[kx * 2 + 3]};
      bscP[jj] = f16x2{(_Float16)bse[kx], (_Float16)bse[kx + 1]};
    } else {
      wsaP[jj] = f16x2{(_Float16)0.f, (_Float16)0.f};
      wsbP[jj] = wsaP[jj];
      bscP[jj] = wsaP[jj];
    }
  }
  const f16x2 cA = f16x2{(_Float16)0.505f, (_Float16)0.505f};
  const f16x2 cB = f16x2{(_Float16)0.495f, (_Float16)0.495f};
  const uint32_t qmask = (q < 2) ? 0xFFFFFFFFu : 0u;

  // x fragment from a rel pair: pk_fma + bitmask lrelu (0.505x + 0.495|x|)
  auto build_x = [&](float r0f, float r1f) -> f16x8 {
    f16x2 r0h = f16x2{(_Float16)r0f, (_Float16)r0f};
    f16x2 r1h = f16x2{(_Float16)r1f, (_Float16)r1f};
    f16x8 xr;
#pragma unroll
    for (int jj = 0; jj < 4; ++jj) {
      f16x2 t = r0h * wsaP[jj] + (r1h * wsbP[jj] + bscP[jj]);
      uint32_t tu = __builtin_bit_cast(uint32_t, t);
      f16x2 ta = __builtin_bit_cast(f16x2, tu & 0x7FFF7FFFu);  // |t|
      f16x2 lr = cA * t + cB * ta;
      lr = __builtin_bit_cast(f16x2, __builtin_bit_cast(uint32_t, lr) & qmask);
      xr[2 * jj] = lr[0];
      xr[2 * jj + 1] = lr[1];
    }
    return xr;
  };

  const f32x4 z = {0.f, 0.f, 0.f, 0.f};
  // ---- goal term via MFMA (once): G[batch] in rel's C/D layout ----
  f32x4 Gacc = z;
#pragma unroll
  for (int kk = 0; kk < 2; ++kk) {
    f16x8 ag, bm;
#pragma unroll
    for (int j = 0; j < 8; ++j) {
      int k = kk * 32 + q * 8 + j;
      ag[j] = (_Float16)goals[(bbase + n) * 64 + k];
      float mv = (n == 0) ? wsf[k] : ((n == 1) ? wsf[64 + k] : 0.f);
      bm[j] = (_Float16)mv;
    }
    Gacc = __builtin_amdgcn_mfma_f32_16x16x32_f16(ag, bm, Gacc, 0, 0, 0);
  }

  // ---- per-batch state: reg r <-> batch 4q+r ----
  float axv[4], ayv[4], cst[4];
#pragma unroll
  for (int r = 0; r < 4; ++r) {
    const int b = bbase + 4 * q + r;
    axv[r] = tabs[b * 2 + 0];
    ayv[r] = tabs[b * 2 + 1];
    cst[r] = c0[b * 64 + hs + n];
    hbuf[(4 * q + r) * 72 + hs + n] = (_Float16)h0[b * 64 + hs + n];
  }

  // ---- x_0 = lrelu(trel @ Wse^T + bse), lane's batch = n ----
  f16x8 xf = build_x(trel[(bbase + n) * 2 + 0], trel[(bbase + n) * 2 + 1]);

  int p = 0;
  for (int s = 0; s <= SEQL; ++s) {
    __syncthreads();  // hbuf[p] holds h_s for all 64 hidden units
    const _Float16* hb = &hbuf[p * 1152];
    f16x8 ah0 = *(const f16x8*)(hb + n * 72 + q * 8);
    f16x8 ah1 = *(const f16x8*)(hb + n * 72 + 32 + q * 8);

    if (s > 0) {
      // rel_{s-1} = h_s @ W_h2p_h^T + goal/abs folded terms
      f32x4 pa = __builtin_amdgcn_mfma_f32_16x16x32_f16(ah0, bp0, z, 0, 0, 0);
      pa = __builtin_amdgcn_mfma_f32_16x16x32_f16(ah1, bp1, pa, 0, 0, 0);
      float u[4];
#pragma unroll
      for (int r = 0; r < 4; ++r)
        u[r] = pa[r] + Gacc[r] + SbCn + fmaf(axv[r], Sxn, ayv[r] * Syn);
      // owner lanes publish rel to this wave's scratch
      if (n < 2) {
#pragma unroll
        for (int r = 0; r < 4; ++r) relbuf[w][4 * q + r][n] = u[r];
      }
      // abs_pos update at owner lanes (partner via one shfl_xor per r)
#pragma unroll
      for (int r = 0; r < 4; ++r) {
        float v = __shfl_xor(u[r], 1, 64);
        float r0 = np ? v : u[r];
        float r1 = np ? u[r] : v;
        axv[r] += r0;
        ayv[r] += r1;
      }
      if (w == 0 && n < 2) {
#pragma unroll
        for (int r = 0; r < 4; ++r)
          outp[((size_t)(s - 1) * B_TOT + bbase + 4 * q + r) * 2 + n] = u[r];
      }
      // x_s rebuild: lane's batch = n reads its rel pair (same-wave LDS)
      float2 rp = *(const float2*)&relbuf[w][n][0];
      xf = build_x(rp.x, rp.y);
    }

    if (s < SEQL) {
      f32x4 acc[4];
#pragma unroll
      for (int g = 0; g < 4; ++g) {
        f32x4 a = {bias[g], bias[g], bias[g], bias[g]};
        a = __builtin_amdgcn_mfma_f32_16x16x32_f16(ah0, bw[g][0], a, 0, 0, 0);
        a = __builtin_amdgcn_mfma_f32_16x16x32_f16(ah1, bw[g][1], a, 0, 0, 0);
        a = __builtin_amdgcn_mfma_f32_16x16x32_f16(xf, bw[g][2], a, 0, 0, 0);
        acc[g] = a;
      }
      _Float16* hw = &hbuf[(p ^ 1) * 1152];
#pragma unroll
      for (int r = 0; r < 4; ++r) {
        float iv = fsigmoid(acc[0][r]);
        float fv = fsigmoid(acc[1][r]);
        float gv = ftanh(acc[2][r]);
        float ov = fsigmoid(acc[3][r]);
        cst[r] = fmaf(fv, cst[r], iv * gv);
        float hn = ov * ftanh(cst[r]);
        hw[(4 * q + r) * 72 + hs + n] = (_Float16)hn;
      }
      p ^= 1;
    }
  }
}

extern "C" void kernel_launch(void* const* d_in, const int* in_sizes, int n_in,
                              void* d_out, int out_size, void* d_ws,
                              size_t ws_size, hipStream_t stream) {
  (void)in_sizes; (void)n_in; (void)out_size; (void)ws_size;
  const float* tabs  = (const float*)d_in[0];
  const float* trel  = (const float*)d_in[1];
  const float* h0    = (const float*)d_in[2];
  const float* c0    = (const float*)d_in[3];
  const float* goals = (const float*)d_in[4];
  const float* Wih   = (const float*)d_in[5];
  const float* Whh   = (const float*)d_in[6];
  const float* bih   = (const float*)d_in[7];
  const float* bhh   = (const float*)d_in[8];
  const float* Wse   = (const float*)d_in[9];
  const float* bse   = (const float*)d_in[10];
  const float* Wh2p  = (const float*)d_in[11];
  const float* bh2p  = (const float*)d_in[12];
  const float* Wgoal = (const float*)d_in[13];
  const float* bgoal = (const float*)d_in[14];
  const float* Wabs  = (const float*)d_in[15];
  const float* babs  = (const float*)d_in[16];
  float* wsf = (float*)d_ws;

  setup_consts<<<dim3(1), dim3(128), 0, stream>>>(Wgoal, bgoal, Wh2p, bh2p,
                                                  Wabs, babs, wsf);
  // 8192 blocks * 16 batch/block = 131072
  lstm_mfma<<<dim3(8192), dim3(256), 0, stream>>>(
      tabs, trel, h0, c0, goals, Wih, Whh, bih, bhh, Wse, bse, Wh2p, wsf,
      (float*)d_out);
}

// Round 5
// 550.907 us; speedup vs baseline: 4.4481x; 1.0647x over previous
//
#include <hip/hip_runtime.h>
#include <stdint.h>

// GoalDecoderLSTM: B=131072 indep LSTM decoders, H=64, E=16, SEQ=30. f32 I/O.
// R5: VALU issue-cycle surgery on the R4 structure (issue-bound: VALU 75.6%
// + MFMA 19.3%). Changes vs R4:
//  - rel/u/ax/ay/store: wave 0 ONLY, published via 64B LDS + 2nd barrier
//    (was computed redundantly in all 4 waves)
//  - fused activations sharing rcp: sig(i)*tanh(g) = (B-1)*rcp((1+A)(B+1));
//    8 transcendentals/elem instead of 10 (overflow needs |arg|>44, bound ~33)
//  - bias enters gate MFMA via spare K-slot k=80 (xf==1 at q2/j0, bias row in
//    bw[g][2]) with a shared zero C -> kills 16 per-step v_mov splats
//  - goal+const folded as C-operand of the rel MFMA chain (GaccP)
//  - dead qmask dropped (B-frag already zero for q>=2), running out-ptr,
//    XOR-toggled LDS double-buffer offsets

#define B_TOT 131072
#define SEQL 30

typedef _Float16 f16x8 __attribute__((ext_vector_type(8)));
typedef _Float16 f16x2 __attribute__((ext_vector_type(2)));
typedef float f32x4 __attribute__((ext_vector_type(4)));

__device__ __forceinline__ float fexp2(float x) {
#if __has_builtin(__builtin_amdgcn_exp2f)
  return __builtin_amdgcn_exp2f(x);
#else
  return exp2f(x);
#endif
}
__device__ __forceinline__ float frcp(float x) {
#if __has_builtin(__builtin_amdgcn_rcpf)
  return __builtin_amdgcn_rcpf(x);
#else
  return 1.0f / x;
#endif
}

// ws layout (floats): [0:64] M0, [64:128] M1,
// [128..135] Sx0,Sx1,Sy0,Sy1,Sb0,Sb1,C00,C01.
__global__ void setup_consts(const float* __restrict__ Wgoal,
                             const float* __restrict__ bgoal,
                             const float* __restrict__ Wh2p,
                             const float* __restrict__ bh2p,
                             const float* __restrict__ Wabs,
                             const float* __restrict__ babs,
                             float* __restrict__ wsf) {
  const int tid = threadIdx.x;
  const int wv = tid >> 6;
  const int lane = tid & 63;
  if (wv == 0) {
    const int k = lane;
    float s0 = 0.f, s1 = 0.f;
#pragma unroll 8
    for (int jj = 0; jj < 64; ++jj) {
      float wg = Wgoal[jj * 64 + k];
      s0 += wg * Wh2p[128 + jj];
      s1 += wg * Wh2p[320 + jj];
    }
    wsf[k] = s0;
    wsf[64 + k] = s1;
  } else {
    const int i = lane >> 3, sub = lane & 7;
    const int p = i & 1, grp = i >> 1;
    float s = 0.f;
#pragma unroll
    for (int t = 0; t < 8; ++t) {
      int j = sub * 8 + t;
      float wv_ = (grp < 3) ? Wh2p[p * 192 + 64 + j] : Wh2p[p * 192 + 128 + j];
      float av = (grp == 0)   ? Wabs[j * 2 + 0]
                 : (grp == 1) ? Wabs[j * 2 + 1]
                 : (grp == 2) ? babs[j]
                              : bgoal[j];
      s += av * wv_;
    }
    s += __shfl_xor(s, 1, 64);
    s += __shfl_xor(s, 2, 64);
    s += __shfl_xor(s, 4, 64);
    if (sub == 0) {
      if (grp == 2) s += bh2p[p];
      wsf[128 + i] = s;
    }
  }
}

__global__ __launch_bounds__(256, 3) void lstm_mfma(
    const float* __restrict__ tabs, const float* __restrict__ trel,
    const float* __restrict__ h0, const float* __restrict__ c0,
    const float* __restrict__ goals, const float* __restrict__ Wih,
    const float* __restrict__ Whh, const float* __restrict__ bih,
    const float* __restrict__ bhh, const float* __restrict__ Wse,
    const float* __restrict__ bse, const float* __restrict__ Wh2p,
    const float* __restrict__ wsf, float* __restrict__ outp) {
  const int lane = threadIdx.x & 63;
  const int w = threadIdx.x >> 6;  // wave: hidden slice [16w,16w+16)
  const int q = lane >> 4;         // quad
  const int n = lane & 15;         // N-col / batch-row index
  const int hs = 16 * w;
  const int bbase = blockIdx.x * 16;

  __shared__ __align__(16) _Float16 hbuf[2 * 16 * 72];  // stride 72: 2-way ok
  __shared__ __align__(8) float relbuf[16][2];          // wave0 -> all

  // ---- gate weight B-frags: B[k][gcol]=Wcat[gcol][k]; gcol=g*64+hs+n ----
  // bw[g][2] k=64+q*8+j: q<2 -> Wih; q==2,j==0 -> bias (paired with xf==1).
  f16x8 bw[4][3];
#pragma unroll
  for (int g = 0; g < 4; ++g) {
    const int row = g * 64 + hs + n;
#pragma unroll
    for (int kk = 0; kk < 2; ++kk)
#pragma unroll
      for (int j = 0; j < 8; ++j)
        bw[g][kk][j] = (_Float16)Whh[row * 64 + kk * 32 + q * 8 + j];
    float bias = bih[row] + bhh[row];
#pragma unroll
    for (int j = 0; j < 8; ++j) {
      float v = (q < 2) ? Wih[row * 16 + q * 8 + j]
                        : ((q == 2 && j == 0) ? bias : 0.f);
      bw[g][2][j] = (_Float16)v;
    }
  }
  // ---- rel projection B-frags (wave0 uses; cols>=2 zero) ----
  f16x8 bp0, bp1;
#pragma unroll
  for (int kk = 0; kk < 2; ++kk)
#pragma unroll
    for (int j = 0; j < 8; ++j) {
      int k = kk * 32 + q * 8 + j;
      float v = (n == 0) ? Wh2p[k] : ((n == 1) ? Wh2p[192 + k] : 0.f);
      if (kk == 0) bp0[j] = (_Float16)v; else bp1[j] = (_Float16)v;
    }
  const int np = (n == 1) ? 1 : 0;
  const float Sxn = wsf[128 + np], Syn = wsf[130 + np];
  const float SbCn = wsf[132 + np] + wsf[134 + np];

  // ---- Wse consts as pk pairs; bscP[0] at q==2 carries the 1.0 bias key ----
  f16x2 wsaP[4], wsbP[4], bscP[4];
#pragma unroll
  for (int jj = 0; jj < 4; ++jj) {
    if (q < 2) {
      int kx = q * 8 + 2 * jj;
      wsaP[jj] = f16x2{(_Float16)Wse[kx * 2 + 0], (_Float16)Wse[kx * 2 + 2]};
      wsbP[jj] = f16x2{(_Float16)Wse[kx * 2 + 1], (_Float16)Wse[kx * 2 + 3]};
      bscP[jj] = f16x2{(_Float16)bse[kx], (_Float16)bse[kx + 1]};
    } else {
      wsaP[jj] = f16x2{(_Float16)0.f, (_Float16)0.f};
      wsbP[jj] = wsaP[jj];
      // q==2, element 0 (k=80): t = 1.0 -> lrelu(1) = 1 -> bias passthrough
      bscP[jj] = (jj == 0 && q == 2) ? f16x2{(_Float16)1.f, (_Float16)0.f}
                                     : wsaP[jj];
    }
  }
  const f16x2 cA = f16x2{(_Float16)0.505f, (_Float16)0.505f};
  const f16x2 cB = f16x2{(_Float16)0.495f, (_Float16)0.495f};

  auto build_x = [&](float r0f, float r1f) -> f16x8 {
    f16x2 r0h = f16x2{(_Float16)r0f, (_Float16)r0f};
    f16x2 r1h = f16x2{(_Float16)r1f, (_Float16)r1f};
    f16x8 xr;
#pragma unroll
    for (int jj = 0; jj < 4; ++jj) {
      f16x2 t = r0h * wsaP[jj] + (r1h * wsbP[jj] + bscP[jj]);
      uint32_t tu = __builtin_bit_cast(uint32_t, t);
      f16x2 ta = __builtin_bit_cast(f16x2, tu & 0x7FFF7FFFu);  // |t|
      f16x2 lr = cA * t + cB * ta;  // lrelu; garbage cols hit zero B-frags
      xr[2 * jj] = lr[0];
      xr[2 * jj + 1] = lr[1];
    }
    return xr;
  };

  const f32x4 zC = {0.f, 0.f, 0.f, 0.f};
  // ---- goal term (wave0 only): GaccP = goals@M + (Sb+C0), rel C-operand ---
  f32x4 GaccP = zC;
  if (w == 0) {
#pragma unroll
    for (int kk = 0; kk < 2; ++kk) {
      f16x8 ag, bm;
#pragma unroll
      for (int j = 0; j < 8; ++j) {
        int k = kk * 32 + q * 8 + j;
        ag[j] = (_Float16)goals[(bbase + n) * 64 + k];
        float mv = (n == 0) ? wsf[k] : ((n == 1) ? wsf[64 + k] : 0.f);
        bm[j] = (_Float16)mv;
      }
      GaccP = __builtin_amdgcn_mfma_f32_16x16x32_f16(ag, bm, GaccP, 0, 0, 0);
    }
#pragma unroll
    for (int r = 0; r < 4; ++r) GaccP[r] += SbCn;
  }

  // ---- per-batch state: reg r <-> batch 4q+r ----
  float axv[4], ayv[4], cst[4];
#pragma unroll
  for (int r = 0; r < 4; ++r) {
    const int b = bbase + 4 * q + r;
    cst[r] = c0[b * 64 + hs + n];
    hbuf[(4 * q + r) * 72 + hs + n] = (_Float16)h0[b * 64 + hs + n];
    if (w == 0) {
      axv[r] = tabs[b * 2 + 0];
      ayv[r] = tabs[b * 2 + 1];
    }
  }

  f16x8 xf = build_x(trel[(bbase + n) * 2 + 0], trel[(bbase + n) * 2 + 1]);

  const int ro = n * 72 + q * 8;
  const int wo = (4 * q) * 72 + hs + n;
  float* op = outp + ((size_t)(bbase + 4 * q) * 2 + n);  // += 2*B_TOT / step
  const float K1 = -1.4426950408889634f;
  const float K2 = 2.8853900817779268f;

  int poff = 0;
  for (int s = 0; s <= SEQL; ++s) {
    __syncthreads();  // hbuf[poff] holds h_s for all 64 hidden units
    const f16x8 ah0 = *(const f16x8*)(hbuf + poff + ro);
    const f16x8 ah1 = *(const f16x8*)(hbuf + poff + ro + 32);

    if (s > 0) {
      if (w == 0) {
        f32x4 pa =
            __builtin_amdgcn_mfma_f32_16x16x32_f16(ah0, bp0, GaccP, 0, 0, 0);
        pa = __builtin_amdgcn_mfma_f32_16x16x32_f16(ah1, bp1, pa, 0, 0, 0);
        float u[4];
#pragma unroll
        for (int r = 0; r < 4; ++r)
          u[r] = pa[r] + fmaf(axv[r], Sxn, ayv[r] * Syn);
        if (n < 2) {
#pragma unroll
          for (int r = 0; r < 4; ++r) {
            relbuf[4 * q + r][n] = u[r];
            op[2 * r] = u[r];
          }
        }
#pragma unroll
        for (int r = 0; r < 4; ++r) {
          float v = __shfl_xor(u[r], 1, 64);
          axv[r] += np ? v : u[r];
          ayv[r] += np ? u[r] : v;
        }
        op += 2 * B_TOT;
      }
      __syncthreads();  // relbuf ready for all waves
      float2 rp = *(const float2*)&relbuf[n][0];
      xf = build_x(rp.x, rp.y);
    }

    if (s < SEQL) {
      f32x4 acc[4];
#pragma unroll
      for (int g = 0; g < 4; ++g) {
        // bias enters via xf(k=80)==1 * bw[g][2][q2,j0]==bias; C = shared 0
        f32x4 a = __builtin_amdgcn_mfma_f32_16x16x32_f16(xf, bw[g][2], zC,
                                                         0, 0, 0);
        a = __builtin_amdgcn_mfma_f32_16x16x32_f16(ah0, bw[g][0], a, 0, 0, 0);
        a = __builtin_amdgcn_mfma_f32_16x16x32_f16(ah1, bw[g][1], a, 0, 0, 0);
        acc[g] = a;
      }
      _Float16* hw = hbuf + (poff ^ 1152) + wo;
#pragma unroll
      for (int r = 0; r < 4; ++r) {
        // fused: sig(i)*tanh(g) = (B-1)*rcp((1+A)(B+1)); ditto sig(o)*tanh(c)
        float A = fexp2(K1 * acc[0][r]);   // e^-i
        float Bv = fexp2(K2 * acc[2][r]);  // e^2g
        float Fv = fexp2(K1 * acc[1][r]);  // e^-f
        float sf = frcp(1.f + Fv);
        float P = (Bv - 1.f) * frcp((1.f + A) * (Bv + 1.f));
        float c = fmaf(sf, cst[r], P);
        cst[r] = c;
        float Cv = fexp2(K1 * acc[3][r]);  // e^-o
        float Dv = fexp2(K2 * c);          // e^2c
        float hn = (Dv - 1.f) * frcp((1.f + Cv) * (Dv + 1.f));
        hw[72 * r] = (_Float16)hn;
      }
      poff ^= 1152;
    }
  }
}

extern "C" void kernel_launch(void* const* d_in, const int* in_sizes, int n_in,
                              void* d_out, int out_size, void* d_ws,
                              size_t ws_size, hipStream_t stream) {
  (void)in_sizes; (void)n_in; (void)out_size; (void)ws_size;
  const float* tabs  = (const float*)d_in[0];
  const float* trel  = (const float*)d_in[1];
  const float* h0    = (const float*)d_in[2];
  const float* c0    = (const float*)d_in[3];
  const float* goals = (const float*)d_in[4];
  const float* Wih   = (const float*)d_in[5];
  const float* Whh   = (const float*)d_in[6];
  const float* bih   = (const float*)d_in[7];
  const float* bhh   = (const float*)d_in[8];
  const float* Wse   = (const float*)d_in[9];
  const float* bse   = (const float*)d_in[10];
  const float* Wh2p  = (const float*)d_in[11];
  const float* bh2p  = (const float*)d_in[12];
  const float* Wgoal = (const float*)d_in[13];
  const float* bgoal = (const float*)d_in[14];
  const float* Wabs  = (const float*)d_in[15];
  const float* babs  = (const float*)d_in[16];
  float* wsf = (float*)d_ws;

  setup_consts<<<dim3(1), dim3(128), 0, stream>>>(Wgoal, bgoal, Wh2p, bh2p,
                                                  Wabs, babs, wsf);
  lstm_mfma<<<dim3(8192), dim3(256), 0, stream>>>(
      tabs, trel, h0, c0, goals, Wih, Whh, bih, bhh, Wse, bse, Wh2p, wsf,
      (float*)d_out);
}

// Round 6
// 528.343 us; speedup vs baseline: 4.6381x; 1.0427x over previous
//
#include <hip/hip_runtime.h>
#include <stdint.h>

// GoalDecoderLSTM: B=131072 indep LSTM decoders, H=64, E=16, SEQ=30. f32 I/O.
// R6: transposed rel-MFMA. R5 post-mortem: wave0-only rel + 2nd barrier cut
// VALU issue (818 cyc/step/wave, as predicted) but idle grew to 13% (waves
// 1-3 stall while wave0 serially computes rel). Fix: compute rel as
// mfma(A=W_h2p-frag, B=ah-frag) -- the A-layout h fragment IS h^T's
// B-fragment -- so D[p][batch] lands lane=batch, reg=p in EVERY wave for ~10
// issue cycles. Deletes: barrier#2, relbuf, shfl_xor ax/ay exchange (ax,ay
// now lane-local), scalar stores (now one coalesced float2 store). Also:
// gate weights/biases prescaled by -log2e (i,f,o) / +2log2e (g) so MFMA accs
// are exp2-ready (kills 4 arg muls/elem), and sigma(f)/P share one rcp via
// common denominator: 7 transcendentals/elem (was 8).

#define B_TOT 131072
#define SEQL 30

typedef _Float16 f16x8 __attribute__((ext_vector_type(8)));
typedef _Float16 f16x2 __attribute__((ext_vector_type(2)));
typedef float f32x4 __attribute__((ext_vector_type(4)));

__device__ __forceinline__ float fexp2(float x) {
#if __has_builtin(__builtin_amdgcn_exp2f)
  return __builtin_amdgcn_exp2f(x);
#else
  return exp2f(x);
#endif
}
__device__ __forceinline__ float frcp(float x) {
#if __has_builtin(__builtin_amdgcn_rcpf)
  return __builtin_amdgcn_rcpf(x);
#else
  return 1.0f / x;
#endif
}

// ws layout (floats): [0:64] M0, [64:128] M1,
// [128..135] Sx0,Sx1,Sy0,Sy1,Sb0,Sb1,C00,C01.
__global__ void setup_consts(const float* __restrict__ Wgoal,
                             const float* __restrict__ bgoal,
                             const float* __restrict__ Wh2p,
                             const float* __restrict__ bh2p,
                             const float* __restrict__ Wabs,
                             const float* __restrict__ babs,
                             float* __restrict__ wsf) {
  const int tid = threadIdx.x;
  const int wv = tid >> 6;
  const int lane = tid & 63;
  if (wv == 0) {
    const int k = lane;
    float s0 = 0.f, s1 = 0.f;
#pragma unroll 8
    for (int jj = 0; jj < 64; ++jj) {
      float wg = Wgoal[jj * 64 + k];
      s0 += wg * Wh2p[128 + jj];
      s1 += wg * Wh2p[320 + jj];
    }
    wsf[k] = s0;
    wsf[64 + k] = s1;
  } else {
    const int i = lane >> 3, sub = lane & 7;
    const int p = i & 1, grp = i >> 1;
    float s = 0.f;
#pragma unroll
    for (int t = 0; t < 8; ++t) {
      int j = sub * 8 + t;
      float wv_ = (grp < 3) ? Wh2p[p * 192 + 64 + j] : Wh2p[p * 192 + 128 + j];
      float av = (grp == 0)   ? Wabs[j * 2 + 0]
                 : (grp == 1) ? Wabs[j * 2 + 1]
                 : (grp == 2) ? babs[j]
                              : bgoal[j];
      s += av * wv_;
    }
    s += __shfl_xor(s, 1, 64);
    s += __shfl_xor(s, 2, 64);
    s += __shfl_xor(s, 4, 64);
    if (sub == 0) {
      if (grp == 2) s += bh2p[p];
      wsf[128 + i] = s;
    }
  }
}

__global__ __launch_bounds__(256, 3) void lstm_mfma(
    const float* __restrict__ tabs, const float* __restrict__ trel,
    const float* __restrict__ h0, const float* __restrict__ c0,
    const float* __restrict__ goals, const float* __restrict__ Wih,
    const float* __restrict__ Whh, const float* __restrict__ bih,
    const float* __restrict__ bhh, const float* __restrict__ Wse,
    const float* __restrict__ bse, const float* __restrict__ Wh2p,
    const float* __restrict__ wsf, float* __restrict__ outp) {
  const int lane = threadIdx.x & 63;
  const int w = threadIdx.x >> 6;  // wave: hidden slice [16w,16w+16)
  const int q = lane >> 4;         // quad
  const int n = lane & 15;         // N-col / batch index
  const int hs = 16 * w;
  const int bbase = blockIdx.x * 16;

  __shared__ __align__(16) _Float16 hbuf[2 * 16 * 72];  // stride 72: 2-way ok

  // ---- gate weight B-frags, PRESCALED so accs are exp2-ready ----
  // i,f,o: *-log2e (acc = -gate*log2e); g: *+2log2e (acc = 2g*log2e)
  const float SI = -1.4426950408889634f;
  const float SG = 2.8853900817779268f;
  const float gsc[4] = {SI, SI, SG, SI};
  f16x8 bw[4][3];
#pragma unroll
  for (int g = 0; g < 4; ++g) {
    const int row = g * 64 + hs + n;
    const float sc = gsc[g];
#pragma unroll
    for (int kk = 0; kk < 2; ++kk)
#pragma unroll
      for (int j = 0; j < 8; ++j)
        bw[g][kk][j] = (_Float16)(sc * Whh[row * 64 + kk * 32 + q * 8 + j]);
    float bias = sc * (bih[row] + bhh[row]);
#pragma unroll
    for (int j = 0; j < 8; ++j) {
      float v = (q < 2) ? sc * Wih[row * 16 + q * 8 + j]
                        : ((q == 2 && j == 0) ? bias : 0.f);
      bw[g][2][j] = (_Float16)v;
    }
  }
  // ---- rel projection as A-frags: A[m=p][k] = W_h2p[p][k] (m<2; else 0) --
  f16x8 awp0, awp1;
#pragma unroll
  for (int j = 0; j < 8; ++j) {
    float v0 = (n < 2) ? Wh2p[n * 192 + q * 8 + j] : 0.f;
    float v1 = (n < 2) ? Wh2p[n * 192 + 32 + q * 8 + j] : 0.f;
    awp0[j] = (_Float16)v0;
    awp1[j] = (_Float16)v1;
  }
  const float Sx0 = wsf[128], Sx1 = wsf[129];
  const float Sy0 = wsf[130], Sy1 = wsf[131];

  // ---- Wse consts as pk pairs; q==2 elem0 carries the 1.0 bias key ----
  f16x2 wsaP[4], wsbP[4], bscP[4];
#pragma unroll
  for (int jj = 0; jj < 4; ++jj) {
    if (q < 2) {
      int kx = q * 8 + 2 * jj;
      wsaP[jj] = f16x2{(_Float16)Wse[kx * 2 + 0], (_Float16)Wse[kx * 2 + 2]};
      wsbP[jj] = f16x2{(_Float16)Wse[kx * 2 + 1], (_Float16)Wse[kx * 2 + 3]};
      bscP[jj] = f16x2{(_Float16)bse[kx], (_Float16)bse[kx + 1]};
    } else {
      wsaP[jj] = f16x2{(_Float16)0.f, (_Float16)0.f};
      wsbP[jj] = wsaP[jj];
      bscP[jj] = (jj == 0 && q == 2) ? f16x2{(_Float16)1.f, (_Float16)0.f}
                                     : wsaP[jj];
    }
  }
  const f16x2 cA = f16x2{(_Float16)0.505f, (_Float16)0.505f};
  const f16x2 cB = f16x2{(_Float16)0.495f, (_Float16)0.495f};

  auto build_x = [&](float r0f, float r1f) -> f16x8 {
    f16x2 r0h = f16x2{(_Float16)r0f, (_Float16)r0f};
    f16x2 r1h = f16x2{(_Float16)r1f, (_Float16)r1f};
    f16x8 xr;
#pragma unroll
    for (int jj = 0; jj < 4; ++jj) {
      f16x2 t = r0h * wsaP[jj] + (r1h * wsbP[jj] + bscP[jj]);
      uint32_t tu = __builtin_bit_cast(uint32_t, t);
      f16x2 ta = __builtin_bit_cast(f16x2, tu & 0x7FFF7FFFu);  // |t|
      f16x2 lr = cA * t + cB * ta;  // lrelu
      xr[2 * jj] = lr[0];
      xr[2 * jj + 1] = lr[1];
    }
    return xr;
  };

  const f32x4 zC = {0.f, 0.f, 0.f, 0.f};
  // ---- goal+const in TRANSPOSED layout: D[p][batch] -> lane=batch, reg=p --
  // A[m=p][k] = M_p[k] (wsf), B[k][batch] = goals[batch][k] (= A-form frag).
  f32x4 GaccT;
  {
    f16x8 aM0, aM1, bg0, bg1;
#pragma unroll
    for (int j = 0; j < 8; ++j) {
      int k = q * 8 + j;
      aM0[j] = (_Float16)((n < 2) ? wsf[n * 64 + k] : 0.f);
      aM1[j] = (_Float16)((n < 2) ? wsf[n * 64 + 32 + k] : 0.f);
      bg0[j] = (_Float16)goals[(bbase + n) * 64 + k];
      bg1[j] = (_Float16)goals[(bbase + n) * 64 + 32 + k];
    }
    GaccT = __builtin_amdgcn_mfma_f32_16x16x32_f16(aM0, bg0, zC, 0, 0, 0);
    GaccT = __builtin_amdgcn_mfma_f32_16x16x32_f16(aM1, bg1, GaccT, 0, 0, 0);
    GaccT[0] += wsf[132] + wsf[134];  // Sb0 + C00
    GaccT[1] += wsf[133] + wsf[135];  // Sb1 + C01
  }

  // ---- per-lane state: ax,ay for batch n (lanes 0-15 authoritative) ----
  float ax = tabs[(bbase + n) * 2 + 0];
  float ay = tabs[(bbase + n) * 2 + 1];
  float cst[4];
#pragma unroll
  for (int r = 0; r < 4; ++r) {
    const int b = bbase + 4 * q + r;
    cst[r] = c0[b * 64 + hs + n];
    hbuf[(4 * q + r) * 72 + hs + n] = (_Float16)h0[b * 64 + hs + n];
  }

  f16x8 xf = build_x(trel[(bbase + n) * 2 + 0], trel[(bbase + n) * 2 + 1]);

  const int ro = n * 72 + q * 8;
  const int wo = (4 * q) * 72 + hs + n;
  const float K2 = 2.8853900817779268f;

  int poff = 0;
  for (int s = 0; s <= SEQL; ++s) {
    __syncthreads();  // hbuf[poff] holds h_s for all 64 hidden units
    const f16x8 ah0 = *(const f16x8*)(hbuf + poff + ro);
    const f16x8 ah1 = *(const f16x8*)(hbuf + poff + ro + 32);

    if (s > 0) {
      // rel_{s-1}: D[p][batch] = sum_k W_h2p[p][k] h[batch][k]; lane=batch.
      f32x4 pa =
          __builtin_amdgcn_mfma_f32_16x16x32_f16(awp0, ah0, GaccT, 0, 0, 0);
      pa = __builtin_amdgcn_mfma_f32_16x16x32_f16(awp1, ah1, pa, 0, 0, 0);
      float u0 = pa[0] + fmaf(ax, Sx0, ay * Sy0);
      float u1 = pa[1] + fmaf(ax, Sx1, ay * Sy1);
      ax += u0;
      ay += u1;
      if (w == 0 && lane < 16) {
        float2 v;
        v.x = u0;
        v.y = u1;
        ((float2*)outp)[(size_t)(s - 1) * B_TOT + bbase + lane] = v;
      }
      // broadcast batch-n rel to all quads (src lanes 0-15 authoritative)
      float r0b = __shfl(u0, n, 64);
      float r1b = __shfl(u1, n, 64);
      xf = build_x(r0b, r1b);
    }

    if (s < SEQL) {
      f32x4 acc[4];
#pragma unroll
      for (int g = 0; g < 4; ++g) {
        f32x4 a = __builtin_amdgcn_mfma_f32_16x16x32_f16(ah0, bw[g][0], zC,
                                                         0, 0, 0);
        a = __builtin_amdgcn_mfma_f32_16x16x32_f16(ah1, bw[g][1], a, 0, 0, 0);
        a = __builtin_amdgcn_mfma_f32_16x16x32_f16(xf, bw[g][2], a, 0, 0, 0);
        acc[g] = a;
      }
      _Float16* hw = hbuf + (poff ^ 1152) + wo;
#pragma unroll
      for (int r = 0; r < 4; ++r) {
        // accs prescaled: acc0=-i*log2e, acc1=-f*log2e, acc2=2g*log2e,
        // acc3=-o*log2e. sig(i)tanh(g) = (B-1)/((1+A)(B+1));
        // c = [cst*(1+A)(B+1) + (B-1)(1+F)] / [(1+A)(B+1)(1+F)]  (one rcp)
        float A = fexp2(acc[0][r]);
        float Fv = fexp2(acc[1][r]);
        float Bv = fexp2(acc[2][r]);
        float t1 = 1.f + A;
        float t2 = Bv + 1.f;
        float t3 = 1.f + Fv;
        float t4 = Bv - 1.f;
        float m1 = t1 * t2;
        float num = fmaf(cst[r], m1, t4 * t3);
        float c = num * frcp(m1 * t3);
        cst[r] = c;
        float Cv = fexp2(acc[3][r]);
        float Dv = fexp2(K2 * c);
        float hn = (Dv - 1.f) * frcp((1.f + Cv) * (Dv + 1.f));
        hw[72 * r] = (_Float16)hn;
      }
      poff ^= 1152;
    }
  }
}

extern "C" void kernel_launch(void* const* d_in, const int* in_sizes, int n_in,
                              void* d_out, int out_size, void* d_ws,
                              size_t ws_size, hipStream_t stream) {
  (void)in_sizes; (void)n_in; (void)out_size; (void)ws_size;
  const float* tabs  = (const float*)d_in[0];
  const float* trel  = (const float*)d_in[1];
  const float* h0    = (const float*)d_in[2];
  const float* c0    = (const float*)d_in[3];
  const float* goals = (const float*)d_in[4];
  const float* Wih   = (const float*)d_in[5];
  const float* Whh   = (const float*)d_in[6];
  const float* bih   = (const float*)d_in[7];
  const float* bhh   = (const float*)d_in[8];
  const float* Wse   = (const float*)d_in[9];
  const float* bse   = (const float*)d_in[10];
  const float* Wh2p  = (const float*)d_in[11];
  const float* bh2p  = (const float*)d_in[12];
  const float* Wgoal = (const float*)d_in[13];
  const float* bgoal = (const float*)d_in[14];
  const float* Wabs  = (const float*)d_in[15];
  const float* babs  = (const float*)d_in[16];
  float* wsf = (float*)d_ws;

  setup_consts<<<dim3(1), dim3(128), 0, stream>>>(Wgoal, bgoal, Wh2p, bh2p,
                                                  Wabs, babs, wsf);
  lstm_mfma<<<dim3(8192), dim3(256), 0, stream>>>(
      tabs, trel, h0, c0, goals, Wih, Whh, bih, bhh, Wse, bse, Wh2p, wsf,
      (float*)d_out);
}